// Round 10
// baseline (27.343 us; speedup 1.0000x reference)
//
#include <hip/hip_runtime.h>

// Chamfer distance via MFMA, LDS-staged ref panel: x,y (32,2048,3) f32 -> scalar.
// d(q,r) = |r|^2 - 2 q.r + |q|^2 as a K=16 bf16 dot (hi/lo split, ~1e-4 err):
//   ref  row A[16] = [xh,xl,xh,xl, yh,yl,yh,yl, zh,zl,zh,zl, nh,nl, 1, 1 ]
//   query col B[16] = [-2qxh,-2qxh,-2qxl,-2qxl, ..y,z.., 1,1, qnh,qnl]
// One v_mfma_f32_32x32x16_bf16 -> 32 refs x 32 queries; refs as A rows makes
// the per-query min within-lane (tree-min + one shfl_xor(32)).
//
// LDS layout (the round-9 fix): [tile][k-half][slot32] --
//   uint idx = (p>>5)*256 + half*128 + (p&31)*4.
// Read:  lane l -> byte t*1024 + (l>>5)*512 + (l&31)*16: 64 contiguous 16B
//        granules = conflict-free 8-round ds_read_b128 (was 8-way conflicted).
// Write: 2x ds_write_b128/point, contiguous 512B per half-wave = conflict-free
//        (was 16-way conflicted ds_write_b32 at stride 32B).
//
// K1: 512 blocks x 256 thr = (dir, batch, 256-query group); pack+stage panel,
//     4 waves x 2 query stripes, 64 tiles: ds_read_b128 + 2 MFMA + tree-min.
// K2: sum 512 partials, scale by 1/(B*N).

#define B_  32
#define N_  2048
#define PTS (B_ * N_)
#define ONEB 0x3F80u

typedef short  bf16x8 __attribute__((ext_vector_type(8)));
typedef float  f32x16 __attribute__((ext_vector_type(16)));

__device__ __forceinline__ unsigned short f2b(float f) {
    unsigned u = __float_as_uint(f);
    return (unsigned short)((u + 0x7FFFu + ((u >> 16) & 1u)) >> 16);  // RNE
}
__device__ __forceinline__ float b2f(unsigned short h) {
    return __uint_as_float(((unsigned)h) << 16);
}
#define PK(a, b) (((unsigned)(a)) | (((unsigned)(b)) << 16))

__global__ __launch_bounds__(256) void chamfer_mfma_kernel(
    const float* __restrict__ x, const float* __restrict__ y,
    float* __restrict__ partial)
{
    __shared__ unsigned sB[N_ * 8];   // 64 KB, swizzled layout (see header)

    const int bid  = blockIdx.x;      // 512
    const int dir  = bid >> 8;
    const int b    = (bid >> 3) & 31;
    const int qg   = bid & 7;         // 8 groups of 256 queries
    const int tid  = threadIdx.x;
    const int lane = tid & 63;
    const int wv   = tid >> 6;
    const int h    = lane >> 5;       // k-half
    const int ln31 = lane & 31;

    const float* q = dir ? y : x;
    const float* r = dir ? x : y;
    const float* rb = r + (size_t)b * N_ * 3;
    const float* qb = q + ((size_t)b * N_ + qg * 256 + wv * 64) * 3;

    // ---- stage ref panel into LDS (8 points per thread) ----
    for (int p = tid; p < N_; p += 256) {
        const float vx = rb[3 * p + 0], vy = rb[3 * p + 1], vz = rb[3 * p + 2];
        const unsigned short xh = f2b(vx), xl = f2b(vx - b2f(xh));
        const unsigned short yh = f2b(vy), yl = f2b(vy - b2f(yh));
        const unsigned short zh = f2b(vz), zl = f2b(vz - b2f(zh));
        const float nrm = fmaf(vx, vx, fmaf(vy, vy, vz * vz));
        const unsigned short nh = f2b(nrm), nl = f2b(nrm - b2f(nh));
        const unsigned base = ((unsigned)(p >> 5)) * 256u + ((unsigned)(p & 31)) * 4u;
        const uint4 lo = make_uint4(PK(xh, xl), PK(xh, xl), PK(yh, yl), PK(yh, yl));
        const uint4 hi = make_uint4(PK(zh, zl), PK(zh, zl), PK(nh, nl), PK(ONEB, ONEB));
        *(uint4*)(sB + base)        = lo;   // k-half 0
        *(uint4*)(sB + base + 128)  = hi;   // k-half 1
    }

    // ---- build 2 query B-frags in registers (stripe s: queries +s*32) ----
    bf16x8 bq[2];
    #pragma unroll
    for (int s = 0; s < 2; ++s) {
        const float* qp = qb + (size_t)(s * 32 + ln31) * 3;
        const float vx = qp[0], vy = qp[1], vz = qp[2];
        const unsigned short xh = f2b(vx), xl = f2b(vx - b2f(xh));
        const unsigned short yh = f2b(vy), yl = f2b(vy - b2f(yh));
        const unsigned short zh = f2b(vz), zl = f2b(vz - b2f(zh));
        const float nrm = fmaf(vx, vx, fmaf(vy, vy, vz * vz));
        const unsigned short nh = f2b(nrm), nl = f2b(nrm - b2f(nh));
        const unsigned short mxh = f2b(-2.0f * b2f(xh)), mxl = f2b(-2.0f * b2f(xl));
        const unsigned short myh = f2b(-2.0f * b2f(yh)), myl = f2b(-2.0f * b2f(yl));
        const unsigned short mzh = f2b(-2.0f * b2f(zh)), mzl = f2b(-2.0f * b2f(zl));
        unsigned u[4];
        if (h == 0) {
            u[0] = PK(mxh, mxh); u[1] = PK(mxl, mxl);
            u[2] = PK(myh, myh); u[3] = PK(myl, myl);
        } else {
            u[0] = PK(mzh, mzh); u[1] = PK(mzl, mzl);
            u[2] = PK(ONEB, ONEB); u[3] = PK(nh, nl);
        }
        bq[s] = *(bf16x8*)u;
    }
    __syncthreads();

    // ---- main loop: 64 ref tiles ----
    const f32x16 zacc = {};
    float macc0 = 3.4e38f, macc1 = 3.4e38f;
    const unsigned roff = (unsigned)h * 128u + (unsigned)ln31 * 4u;

    #pragma unroll 2
    for (int t = 0; t < 64; ++t) {
        const bf16x8 af = *(const bf16x8*)(sB + t * 256 + roff);
        const f32x16 d0 = __builtin_amdgcn_mfma_f32_32x32x16_bf16(af, bq[0], zacc, 0, 0, 0);
        const f32x16 d1 = __builtin_amdgcn_mfma_f32_32x32x16_bf16(af, bq[1], zacc, 0, 0, 0);
        float m0a = fminf(fminf(d0[0], d0[1]), fminf(d0[2], d0[3]));
        float m0b = fminf(fminf(d0[4], d0[5]), fminf(d0[6], d0[7]));
        float m0c = fminf(fminf(d0[8], d0[9]), fminf(d0[10], d0[11]));
        float m0d = fminf(fminf(d0[12], d0[13]), fminf(d0[14], d0[15]));
        macc0 = fminf(macc0, fminf(fminf(m0a, m0b), fminf(m0c, m0d)));
        float m1a = fminf(fminf(d1[0], d1[1]), fminf(d1[2], d1[3]));
        float m1b = fminf(fminf(d1[4], d1[5]), fminf(d1[6], d1[7]));
        float m1c = fminf(fminf(d1[8], d1[9]), fminf(d1[10], d1[11]));
        float m1d = fminf(fminf(d1[12], d1[13]), fminf(d1[14], d1[15]));
        macc1 = fminf(macc1, fminf(fminf(m1a, m1b), fminf(m1c, m1d)));
    }

    // ---- combine k-halves (other 16 rows live in the partner half-wave) ----
    macc0 = fminf(macc0, __shfl_xor(macc0, 32));
    macc1 = fminf(macc1, __shfl_xor(macc1, 32));

    // ---- sum the 64 per-query mins of this wave ----
    float s = macc0 + macc1;
    s += __shfl_xor(s, 1);
    s += __shfl_xor(s, 2);
    s += __shfl_xor(s, 4);
    s += __shfl_xor(s, 8);
    s += __shfl_xor(s, 16);

    __syncthreads();                              // sB done; reuse as sred
    float* sred = (float*)sB;
    if (lane == 0) sred[wv] = s;
    __syncthreads();
    if (tid == 0) partial[bid] = (sred[0] + sred[1]) + (sred[2] + sred[3]);
}

__global__ __launch_bounds__(256) void chamfer_final_kernel(
    const float* __restrict__ partial, float* __restrict__ out)
{
    const int tid = threadIdx.x;
    float s = partial[tid] + partial[tid + 256];
    #pragma unroll
    for (int off = 32; off > 0; off >>= 1) s += __shfl_down(s, off);
    __shared__ float sr[4];
    if ((tid & 63) == 0) sr[tid >> 6] = s;
    __syncthreads();
    if (tid == 0)
        out[0] = ((sr[0] + sr[1]) + (sr[2] + sr[3])) * (1.0f / (float)PTS);
}

extern "C" void kernel_launch(void* const* d_in, const int* in_sizes, int n_in,
                              void* d_out, int out_size, void* d_ws, size_t ws_size,
                              hipStream_t stream)
{
    const float* x = (const float*)d_in[0];
    const float* y = (const float*)d_in[1];
    float* partial = (float*)d_ws;            // 512 floats
    float* out     = (float*)d_out;

    chamfer_mfma_kernel<<<512, 256, 0, stream>>>(x, y, partial);
    chamfer_final_kernel<<<1, 256, 0, stream>>>(partial, out);
}

// Round 11
// 16.845 us; speedup vs baseline: 1.6232x; 1.6232x over previous
//
#include <hip/hip_runtime.h>

// Chamfer distance via MFMA, LDS-staged ref panel: x,y (32,2048,3) f32 -> scalar.
// d(q,r) = |r|^2 - 2 q.r + |q|^2 as a K=16 bf16 dot (hi/lo split, ~1e-4 err):
//   ref  row A[16] = [xh,xl,xh,xl, yh,yl,yh,yl, zh,zl,zh,zl, nh,nl, 1, 1 ]
//   query col B[16] = [-2qxh,-2qxh,-2qxl,-2qxl, ..y,z.., 1,1, qnh,qnl]
// One v_mfma_f32_32x32x16_bf16 -> 32 refs x 32 queries; refs as A rows makes
// the per-query min within-lane.
//
// Round-11 structure (latency-hiding fix):
//   512 blocks x 512 threads (8 waves, ONE 32-query stripe each) ->
//   2 blocks/CU = 4 waves/SIMD (was 2).  Running min kept as elementwise
//   f32x16 (depth-1 dep on MFMA result; tree-reduce once in epilogue).
//   Per-iter wave body: 1 ds_read_b128 + 1 MFMA + 16 v_min.
// LDS: conflict-free [tile][k-half][slot32] layout from round 10.
// K2: sum 512 partials, scale by 1/(B*N).

#define B_  32
#define N_  2048
#define PTS (B_ * N_)
#define ONEB 0x3F80u

typedef short  bf16x8 __attribute__((ext_vector_type(8)));
typedef float  f32x16 __attribute__((ext_vector_type(16)));

__device__ __forceinline__ unsigned short f2b(float f) {
    unsigned u = __float_as_uint(f);
    return (unsigned short)((u + 0x7FFFu + ((u >> 16) & 1u)) >> 16);  // RNE
}
__device__ __forceinline__ float b2f(unsigned short h) {
    return __uint_as_float(((unsigned)h) << 16);
}
#define PK(a, b) (((unsigned)(a)) | (((unsigned)(b)) << 16))

__global__ __launch_bounds__(512, 4) void chamfer_mfma_kernel(
    const float* __restrict__ x, const float* __restrict__ y,
    float* __restrict__ partial)
{
    __shared__ unsigned sB[N_ * 8];   // 64 KB, [tile][half][slot32] layout

    const int bid  = blockIdx.x;      // 512
    const int dir  = bid >> 8;
    const int b    = (bid >> 3) & 31;
    const int qg   = bid & 7;         // 8 groups of 256 queries
    const int tid  = threadIdx.x;
    const int lane = tid & 63;
    const int wv   = tid >> 6;        // 0..7
    const int h    = lane >> 5;       // k-half
    const int ln31 = lane & 31;

    const float* q = dir ? y : x;
    const float* r = dir ? x : y;
    const float* rb = r + (size_t)b * N_ * 3;
    const float* qb = q + ((size_t)b * N_ + qg * 256 + wv * 32) * 3;

    // ---- stage ref panel into LDS (4 points per thread) ----
    for (int p = tid; p < N_; p += 512) {
        const float vx = rb[3 * p + 0], vy = rb[3 * p + 1], vz = rb[3 * p + 2];
        const unsigned short xh = f2b(vx), xl = f2b(vx - b2f(xh));
        const unsigned short yh = f2b(vy), yl = f2b(vy - b2f(yh));
        const unsigned short zh = f2b(vz), zl = f2b(vz - b2f(zh));
        const float nrm = fmaf(vx, vx, fmaf(vy, vy, vz * vz));
        const unsigned short nh = f2b(nrm), nl = f2b(nrm - b2f(nh));
        const unsigned base = ((unsigned)(p >> 5)) * 256u + ((unsigned)(p & 31)) * 4u;
        const uint4 lo = make_uint4(PK(xh, xl), PK(xh, xl), PK(yh, yl), PK(yh, yl));
        const uint4 hi = make_uint4(PK(zh, zl), PK(zh, zl), PK(nh, nl), PK(ONEB, ONEB));
        *(uint4*)(sB + base)        = lo;   // k-half 0
        *(uint4*)(sB + base + 128)  = hi;   // k-half 1
    }

    // ---- build this wave's query B-frag (32 queries) ----
    bf16x8 bq;
    {
        const float* qp = qb + (size_t)ln31 * 3;
        const float vx = qp[0], vy = qp[1], vz = qp[2];
        const unsigned short xh = f2b(vx), xl = f2b(vx - b2f(xh));
        const unsigned short yh = f2b(vy), yl = f2b(vy - b2f(yh));
        const unsigned short zh = f2b(vz), zl = f2b(vz - b2f(zh));
        const float nrm = fmaf(vx, vx, fmaf(vy, vy, vz * vz));
        const unsigned short nh = f2b(nrm), nl = f2b(nrm - b2f(nh));
        const unsigned short mxh = f2b(-2.0f * b2f(xh)), mxl = f2b(-2.0f * b2f(xl));
        const unsigned short myh = f2b(-2.0f * b2f(yh)), myl = f2b(-2.0f * b2f(yl));
        const unsigned short mzh = f2b(-2.0f * b2f(zh)), mzl = f2b(-2.0f * b2f(zl));
        unsigned u[4];
        if (h == 0) {
            u[0] = PK(mxh, mxh); u[1] = PK(mxl, mxl);
            u[2] = PK(myh, myh); u[3] = PK(myl, myl);
        } else {
            u[0] = PK(mzh, mzh); u[1] = PK(mzl, mzl);
            u[2] = PK(ONEB, ONEB); u[3] = PK(nh, nl);
        }
        bq = *(bf16x8*)u;
    }
    __syncthreads();

    // ---- main loop: 64 ref tiles, elementwise running min ----
    const f32x16 zacc = {};
    f32x16 maccv = zacc + 3.4e38f;
    const unsigned roff = (unsigned)h * 128u + (unsigned)ln31 * 4u;

    #pragma unroll 4
    for (int t = 0; t < 64; ++t) {
        const bf16x8 af = *(const bf16x8*)(sB + t * 256 + roff);
        const f32x16 d = __builtin_amdgcn_mfma_f32_32x32x16_bf16(af, bq, zacc, 0, 0, 0);
        maccv = __builtin_elementwise_min(maccv, d);
    }

    // ---- epilogue: tree-reduce 16 regs, combine k-halves, sum 32 queries ----
    float m0 = fminf(fminf(maccv[0],  maccv[1]),  fminf(maccv[2],  maccv[3]));
    float m1 = fminf(fminf(maccv[4],  maccv[5]),  fminf(maccv[6],  maccv[7]));
    float m2 = fminf(fminf(maccv[8],  maccv[9]),  fminf(maccv[10], maccv[11]));
    float m3 = fminf(fminf(maccv[12], maccv[13]), fminf(maccv[14], maccv[15]));
    float m  = fminf(fminf(m0, m1), fminf(m2, m3));
    m = fminf(m, __shfl_xor(m, 32));              // other 16 rows

    float s = m;                                   // lanes 0..31 distinct queries
    s += __shfl_xor(s, 1);
    s += __shfl_xor(s, 2);
    s += __shfl_xor(s, 4);
    s += __shfl_xor(s, 8);
    s += __shfl_xor(s, 16);                        // lane 0 (and 32): stripe sum

    __syncthreads();                               // sB done; reuse as sred
    float* sred = (float*)sB;
    if (lane == 0) sred[wv] = s;
    __syncthreads();
    if (tid == 0)
        partial[bid] = ((sred[0] + sred[1]) + (sred[2] + sred[3])) +
                       ((sred[4] + sred[5]) + (sred[6] + sred[7]));
}

__global__ __launch_bounds__(256) void chamfer_final_kernel(
    const float* __restrict__ partial, float* __restrict__ out)
{
    const int tid = threadIdx.x;
    float s = partial[tid] + partial[tid + 256];
    #pragma unroll
    for (int off = 32; off > 0; off >>= 1) s += __shfl_down(s, off);
    __shared__ float sr[4];
    if ((tid & 63) == 0) sr[tid >> 6] = s;
    __syncthreads();
    if (tid == 0)
        out[0] = ((sr[0] + sr[1]) + (sr[2] + sr[3])) * (1.0f / (float)PTS);
}

extern "C" void kernel_launch(void* const* d_in, const int* in_sizes, int n_in,
                              void* d_out, int out_size, void* d_ws, size_t ws_size,
                              hipStream_t stream)
{
    const float* x = (const float*)d_in[0];
    const float* y = (const float*)d_in[1];
    float* partial = (float*)d_ws;            // 512 floats
    float* out     = (float*)d_out;

    chamfer_mfma_kernel<<<512, 512, 0, stream>>>(x, y, partial);
    chamfer_final_kernel<<<1, 256, 0, stream>>>(partial, out);
}